// Round 6
// baseline (1163.278 us; speedup 1.0000x reference)
//
#include <hip/hip_runtime.h>
#include <cstddef>

#define BATCH 512
#define ESZ   256
#define HSZ   512
#define G4    2048      // 4*HS
#define SRCL  64
#define TRGL  48
#define ODIM  67

typedef __bf16  bf8v    __attribute__((ext_vector_type(8)));
typedef __bf16  bf4v    __attribute__((ext_vector_type(4)));
typedef float   floatx4 __attribute__((ext_vector_type(4)));

__device__ __forceinline__ floatx4 MF(bf8v a, bf8v b, floatx4 c) {
    return __builtin_amdgcn_mfma_f32_16x16x32_bf16(a, b, c, 0, 0, 0);
}

// fast transcendentals: v_exp_f32 + v_rcp_f32
__device__ __forceinline__ float frcp(float x) { return __builtin_amdgcn_rcpf(x); }
__device__ __forceinline__ float fsig(float x) { return frcp(1.0f + __expf(-x)); }
__device__ __forceinline__ float ftanh(float x) { return 1.0f - 2.0f * frcp(1.0f + __expf(2.0f * x)); }

__device__ __forceinline__ bf8v cvt8(const float* __restrict__ s) {
    float4 a = *(const float4*)s;
    float4 b = *(const float4*)(s + 4);
    bf8v v;
    v[0] = (__bf16)a.x; v[1] = (__bf16)a.y; v[2] = (__bf16)a.z; v[3] = (__bf16)a.w;
    v[4] = (__bf16)b.x; v[5] = (__bf16)b.y; v[6] = (__bf16)b.z; v[7] = (__bf16)b.w;
    return v;
}

// ---------------- prep kernels ----------------
// encoder embedding into A-frag order: Az[t][mt32][kt8][lane][8]
__global__ void embed_swz(const int* __restrict__ tok, const float* __restrict__ table,
                          __bf16* __restrict__ Az) {
    int i = blockIdx.x * 256 + threadIdx.x;   // 1,048,576 chunks
    int lane = i & 63;
    int kt = (i >> 6) & 7;
    int mt = (i >> 9) & 31;
    int t  = i >> 14;
    int b = mt * 16 + (lane & 15);
    int k = kt * 32 + (lane >> 4) * 8;
    int tk = tok[t * BATCH + b];
    (void)kt;
    *(bf8v*)(Az + (size_t)i * 8) = cvt8(table + (size_t)tk * ESZ + k);
}

// decoder embedding into A-frag order: Dz[mt1504][kt8][lane][8]
__global__ void embdz(const int* __restrict__ trg, const float* __restrict__ table,
                      __bf16* __restrict__ Dz) {
    int i = blockIdx.x * 256 + threadIdx.x;   // 770,048 chunks
    int lane = i & 63;
    int kt = (i >> 6) & 7;
    int mt = i >> 9;                          // 0..1503
    int row = mt * 16 + (lane & 15);          // < 24064
    int k = kt * 32 + (lane >> 4) * 8;
    int tk = trg[row];                        // trg[:-1] rows, (t*512+b) flat
    *(bf8v*)(Dz + (size_t)i * 8) = cvt8(table + (size_t)tk * ESZ + k);
}

__global__ void zero_kernel(float* __restrict__ p, int n) {
    int i = blockIdx.x * 256 + threadIdx.x;
    if (i < n) p[i] = 0.f;
}

__global__ void bias_prep(const float* __restrict__ af, const float* __restrict__ bf,
                          const float* __restrict__ ab, const float* __restrict__ bb,
                          const float* __restrict__ ad, const float* __restrict__ bd,
                          float* __restrict__ of, float* __restrict__ ob, float* __restrict__ od) {
    int i = blockIdx.x * 256 + threadIdx.x;
    if (i < G4) { of[i] = af[i] + bf[i]; ob[i] = ab[i] + bb[i]; od[i] = ad[i] + bd[i]; }
}

// encoder weights into B-frag order: Wz[jt32][g4][kt24][lane][8]
__global__ void wswz_bf16(const float* __restrict__ Wih, const float* __restrict__ Whh,
                          __bf16* __restrict__ Wz) {
    int i = blockIdx.x * 256 + threadIdx.x;   // 196,608 chunks
    int lane = i & 63;
    int rest = i >> 6;
    int kt = rest % 24;
    int gj = rest / 24;                        // jt*4+g
    int g = gj & 3, jt = gj >> 2;
    int row = g * 512 + jt * 16 + (lane & 15);
    int k = kt * 32 + (lane >> 4) * 8;
    const float* src = (k < ESZ) ? (Wih + (size_t)row * ESZ + k)
                                 : (Whh + (size_t)row * HSZ + (k - ESZ));
    *(bf8v*)(Wz + (size_t)i * 8) = cvt8(src);
}

// decoder emb-weights direct to B-frag order: decWz[nt128][kt8][lane][8], nt = row/16
__global__ void decwz(const float* __restrict__ dec_Wih, __bf16* __restrict__ Wz) {
    int i = blockIdx.x * 256 + threadIdx.x;   // 65,536 chunks
    int lane = i & 63;
    int kt = (i >> 6) & 7;
    int nt = i >> 9;                          // 0..127
    int row = nt * 16 + (lane & 15);
    int k = kt * 32 + (lane >> 4) * 8;
    *(bf8v*)(Wz + (size_t)i * 8) =
        cvt8(dec_Wih + (size_t)row * (2 * HSZ + ESZ) + 2 * HSZ + k);
}

// WdC[n][0:1024]=dec_Wih[n][0:1024], [1024:1536]=dec_Whh[n]  (2048 x 1536 bf16)
__global__ void wdcat_bf16(const float* __restrict__ dec_Wih, const float* __restrict__ dec_Whh,
                           __bf16* __restrict__ Wd) {
    int i = blockIdx.x * 256 + threadIdx.x;
    int n = i / 192;
    int e = (i - n * 192) << 3;
    const float* src = (e < 1024) ? (dec_Wih + (size_t)n * 1280 + e)
                                  : (dec_Whh + (size_t)n * HSZ + (e - 1024));
    *(bf8v*)(Wd + (size_t)n * 1536 + e) = cvt8(src);
}

__global__ void conv_f2b(const float* __restrict__ src, __bf16* __restrict__ dst, int n8) {
    int i = blockIdx.x * 256 + threadIdx.x;
    if (i < n8) *(bf8v*)(dst + (size_t)i * 8) = cvt8(src + (size_t)i * 8);
}

// fc_out_W padded to 128 rows x 512 bf16
__global__ void fo_pad(const float* __restrict__ W, __bf16* __restrict__ dst) {
    int i = blockIdx.x * 256 + threadIdx.x;
    int r = i >> 6, e = (i & 63) << 3;
    bf8v v;
    if (r < ODIM) v = cvt8(W + (size_t)r * HSZ + e);
    else { for (int k = 0; k < 8; ++k) v[k] = (__bf16)0.f; }
    *(bf8v*)(dst + (size_t)r * HSZ + e) = v;
}

// generic row-major bf16 [N][K] -> frag order [nt][kt][lane][8]
__global__ void fragswz(const __bf16* __restrict__ src, __bf16* __restrict__ dst,
                        int KT, int nchunks) {
    int i = blockIdx.x * 256 + threadIdx.x;
    if (i >= nchunks) return;
    int lane = i & 63;
    int kt = (i >> 6) % KT;
    int nt = (i >> 6) / KT;
    int row = nt * 16 + (lane & 15);
    int k = kt * 32 + (lane >> 4) * 8;
    *(bf8v*)(dst + (size_t)i * 8) = *(const bf8v*)(src + (size_t)row * (KT * 32) + k);
}

// hfb[r] = [es[63][r][0:512] | es[0][r][512:1024]]
__global__ void cat_hfb(const __bf16* __restrict__ es, __bf16* __restrict__ dst) {
    int i = blockIdx.x * 256 + threadIdx.x;
    int r = i >> 7, e = (i & 127) << 3;
    const __bf16* s = (e < HSZ) ? (es + ((size_t)(63 * BATCH + r)) * 1024 + e)
                                : (es + (size_t)r * 1024 + e);
    *(bf8v*)(dst + (size_t)r * 1024 + e) = *(const bf8v*)s;
}

// cfb[r] = bf16([cf[r] | cb[r]]) from cbuf fp32 [2][512][512]
__global__ void cat_cfb(const float* __restrict__ cbuf, __bf16* __restrict__ dst) {
    int i = blockIdx.x * 256 + threadIdx.x;
    int r = i >> 7, e = (i & 127) << 3;
    const float* s = (e < HSZ) ? (cbuf + (size_t)r * HSZ + e)
                               : (cbuf + (size_t)BATCH * HSZ + (size_t)r * HSZ + (e - HSZ));
    *(bf8v*)(dst + (size_t)r * 1024 + e) = cvt8(s);
}

// ctxh[r] = bf16([ctx[r] (1024) | hid_h[r] (512)])
__global__ void cat_ctxh(const float* __restrict__ ctx, const float* __restrict__ hid_h,
                         __bf16* __restrict__ dst) {
    int i = blockIdx.x * 256 + threadIdx.x;
    int r = i / 192;
    int e = (i - r * 192) << 3;
    const float* s = (e < 1024) ? (ctx + (size_t)r * 1024 + e)
                                : (hid_h + (size_t)r * HSZ + (e - 1024));
    *(bf8v*)(dst + (size_t)r * 1536 + e) = cvt8(s);
}

// D0s[(b*512+j)*4 + g] = D0[b*2048 + g*512 + j]
__global__ void d0_swz(const float* __restrict__ D0, float* __restrict__ D0s) {
    int i = blockIdx.x * 256 + threadIdx.x;   // 1048576
    int b = i >> 11, rest = i & 2047, g = rest >> 9, j = rest & 511;
    D0s[(((size_t)b * 512 + j) << 2) + g] = D0[i];
}

// ---------------- encoder step v6 ----------------
// gates = [x_t | h] @ Wcat^T + bias, fused LSTM.
// grid (32 j-tiles-of-16, 8 m-tiles-of-64, 2 dir) = 512 blocks, 256 thr (4 waves, m-split).
// Wave: 16m x 16j x 4 gates (acc[4]). Whh B-slice (64 KB) LDS-staged; x-B from L1/L2.
__global__ __launch_bounds__(256) void enc_step6(
    const __bf16* __restrict__ Az, const __bf16* __restrict__ hPrev,
    __bf16* __restrict__ hNext, float* __restrict__ cbuf, __bf16* __restrict__ es,
    const __bf16* __restrict__ WzF, const __bf16* __restrict__ WzB,
    const float* __restrict__ biasF, const float* __restrict__ biasB, int t)
{
    __shared__ __bf16 Bh[4 * 16 * 64 * 8];    // 64 KB
    __shared__ float  hT[64 * 17];            // 4.4 KB

    const int dir = blockIdx.z;
    const int tt  = dir ? (SRCL - 1 - t) : t;
    const __bf16* Wz  = dir ? WzB : WzF;
    const float* bias = dir ? biasB : biasF;
    const int jt = blockIdx.x;                // 0..31
    const int j0 = jt * 16;
    const int m0 = blockIdx.y * 64;

    const int tid = threadIdx.x;
    const int w = tid >> 6, lane = tid & 63;
    const int quad = lane >> 4, l15 = lane & 15;

    const __bf16* WzJ = Wz + (((size_t)jt * 4 * 24) << 9);   // [g][kt24][64][8]

    // stage Whh B-slice into LDS: Bh[(g*16+ktl)*64+lane] <- WzJ[(g*24+8+ktl)*64+lane]
#pragma unroll
    for (int it = 0; it < 16; ++it) {
        int idx = tid + it * 256;
        *(bf8v*)(Bh + ((size_t)idx << 3)) =
            *(const bf8v*)(WzJ + (((size_t)(((idx >> 10) * 24 + 8 + ((idx >> 6) & 15)) * 64
                                            + (idx & 63))) << 3));
    }

    const int mt = (m0 >> 4) + w;             // tile-of-16 index (0..31)
    floatx4 acc[4] = {};

    // x part: A frag-order from Az, B from global (L1 catches 4-wave dup)
    const __bf16* ax = Az + ((((size_t)tt * 32 + mt) * 8) << 9) + lane * 8;
#pragma unroll
    for (int kt = 0; kt < 8; ++kt) {
        bf8v a = *(const bf8v*)(ax + ((size_t)kt << 9));
#pragma unroll
        for (int g = 0; g < 4; ++g) {
            bf8v b = *(const bf8v*)(WzJ + (((size_t)((g * 24 + kt) * 64 + lane)) << 3));
            acc[g] = MF(a, b, acc[g]);
        }
    }
    __syncthreads();                          // Bh visible
    // h part: A frag-order from hPrev, B from LDS
    const __bf16* ah = hPrev + ((((size_t)dir * 32 + mt) * 16) << 9) + lane * 8;
#pragma unroll 4
    for (int kt = 0; kt < 16; ++kt) {
        bf8v a = *(const bf8v*)(ah + ((size_t)kt << 9));
#pragma unroll
        for (int g = 0; g < 4; ++g) {
            bf8v b = *(const bf8v*)(Bh + (((size_t)((g * 16 + kt) * 64 + lane)) << 3));
            acc[g] = MF(a, b, acc[g]);
        }
    }

    // epilogue: lane owns (m = mt*16 + quad*4 + r, j = j0 + l15), 4 gates in acc[g][r]
    const int j = j0 + l15;
    const float b0 = bias[j], b1 = bias[HSZ + j], b2 = bias[2 * HSZ + j], b3 = bias[3 * HSZ + j];
    const size_t cb = (size_t)dir * BATCH * HSZ;
    const int mwb = w * 16 + quad * 4;        // m within block's 64
#pragma unroll
    for (int r = 0; r < 4; ++r) {
        int m = m0 + mwb + r;
        float gi = acc[0][r] + b0;
        float gf = acc[1][r] + b1;
        float gg = acc[2][r] + b2;
        float go = acc[3][r] + b3;
        size_t ci = cb + (size_t)m * HSZ + j;
        float cn = fsig(gf) * cbuf[ci] + fsig(gi) * ftanh(gg);
        cbuf[ci] = cn;
        hT[(mwb + r) * 17 + l15] = fsig(go) * ftanh(cn);
    }
    __syncthreads();

    // es store (row-major bf16): 64 rows x 16 j
    {
        int r = tid >> 2, ch = tid & 3;
        const float* hp = &hT[r * 17 + ch * 4];
        bf4v v;
#pragma unroll
        for (int e = 0; e < 4; ++e) v[e] = (__bf16)hp[e];
        *(bf4v*)(es + ((size_t)tt * BATCH + m0 + r) * 1024 + dir * HSZ + j0 + ch * 4) = v;
    }
    // h frag-order store: 128 threads, half-chunk (16 j) per mt
    if (tid < 128) {
        int mtl = tid >> 5;                   // 0..3
        int lnsub = tid & 31;
        int jhalf = (j0 >> 4) & 1;
        int ln = lnsub + jhalf * 32;
        int mloc = mtl * 16 + (lnsub & 15);
        int jloc = (lnsub >> 4) * 8;
        const float* hp = &hT[mloc * 17 + jloc];
        bf8v v;
#pragma unroll
        for (int e = 0; e < 8; ++e) v[e] = (__bf16)hp[e];
        size_t chunk = (((size_t)dir * 32 + (m0 >> 4) + mtl) * 16 + (j0 >> 5)) * 64 + ln;
        *(bf8v*)(hNext + chunk * 8) = v;
    }
}

// ---------------- decoder v6: pure-register frag-order GEMM + fused LSTM ----------------
// grid (32 j-tiles-of-16, 94 m-blocks-of-256), 256 thr (4 waves, m-split 64 each).
__global__ __launch_bounds__(256) void dec_v6(
    const __bf16* __restrict__ Dz, const __bf16* __restrict__ Wz,
    const float* __restrict__ D0s, const float* __restrict__ hidc,
    __bf16* __restrict__ h_new)
{
    const int tid = threadIdx.x;
    const int w = tid >> 6, lane = tid & 63;
    const int quad = lane >> 4, l15 = lane & 15;
    const int jt = blockIdx.x;                // 0..31
    const int mt0 = blockIdx.y * 16 + w * 4;  // tiles of 16 rows

    floatx4 acc[4][4] = {};                   // [ms][g]
    const __bf16* az = Dz + (((size_t)mt0 * 8) << 9) + lane * 8;
#pragma unroll
    for (int kt = 0; kt < 8; ++kt) {
        bf8v a[4];
#pragma unroll
        for (int ms = 0; ms < 4; ++ms)
            a[ms] = *(const bf8v*)(az + (((size_t)(ms * 8 + kt)) << 9));
#pragma unroll
        for (int g = 0; g < 4; ++g) {
            bf8v b = *(const bf8v*)(Wz + (((size_t)(((g * 32 + jt) * 8 + kt) * 64 + lane)) << 3));
#pragma unroll
            for (int ms = 0; ms < 4; ++ms)
                acc[ms][g] = MF(a[ms], b, acc[ms][g]);
        }
    }
    const int j = jt * 16 + l15;
#pragma unroll
    for (int ms = 0; ms < 4; ++ms) {
        int mb = (mt0 + ms) * 16 + quad * 4;
#pragma unroll
        for (int r = 0; r < 4; ++r) {
            int m = mb + r;
            int b = m & (BATCH - 1);
            floatx4 d0 = *(const floatx4*)(D0s + (((size_t)b * 512 + j) << 2));
            float gi = acc[ms][0][r] + d0[0];
            float gf = acc[ms][1][r] + d0[1];
            float gg = acc[ms][2][r] + d0[2];
            float go = acc[ms][3][r] + d0[3];
            float cn = fsig(gf) * hidc[(size_t)b * HSZ + j] + fsig(gi) * ftanh(gg);
            h_new[(size_t)m * HSZ + j] = (__bf16)(fsig(go) * ftanh(cn));
        }
    }
}

// ---------------- generic GEMM, frag-order B: C = A @ Bz^T + bias (fp32 out) ----------------
// A row-major [M][K]; Bz frag order [nt][KT][lane][8]. Wave 16m x 64n. grid (N/64, M/64).
__global__ __launch_bounds__(256) void gmmz(
    const __bf16* __restrict__ A, const __bf16* __restrict__ Bz, int K, int KT,
    const float* __restrict__ bias, float* __restrict__ C, int ldc, int N)
{
    const int tid = threadIdx.x;
    const int w = tid >> 6, lane = tid & 63;
    const int quad = lane >> 4, l15 = lane & 15;
    const int n0 = blockIdx.x * 64;
    const int mA = blockIdx.y * 64 + w * 16 + l15;
    const __bf16* Ar = A + (size_t)mA * K + quad * 8;

    floatx4 acc[4] = {};
    for (int kt = 0; kt < KT; ++kt) {
        bf8v a = *(const bf8v*)(Ar + kt * 32);
#pragma unroll
        for (int ns = 0; ns < 4; ++ns) {
            int jt = (n0 >> 4) + ns;
            bf8v b = *(const bf8v*)(Bz + (((size_t)((jt * KT + kt) * 64 + lane)) << 3));
            acc[ns] = MF(a, b, acc[ns]);
        }
    }
    const int mb = blockIdx.y * 64 + w * 16 + quad * 4;
#pragma unroll
    for (int ns = 0; ns < 4; ++ns) {
        int n = n0 + ns * 16 + l15;
        if (n < N) {
#pragma unroll
            for (int r = 0; r < 4; ++r)
                C[(size_t)(mb + r) * ldc + n] = acc[ns][r] + bias[n];
        }
    }
}

// ---------------- attention ----------------
__global__ void eh_kernel(const float* __restrict__ hid_h, const float* __restrict__ eW,
                          const float* __restrict__ eb, float* __restrict__ eh) {
    int w = blockIdx.x * 4 + (threadIdx.x >> 6);
    int lane = threadIdx.x & 63;
    if (w >= BATCH) return;
    float s = 0.f;
    for (int k = lane; k < HSZ; k += 64) s += hid_h[(size_t)w * HSZ + k] * eW[k];
    for (int off = 32; off; off >>= 1) s += __shfl_down(s, off);
    if (lane == 0) eh[w] = s + eb[0];
}

__global__ void energy_kernel(const __bf16* __restrict__ es, const float* __restrict__ eW2,
                              const float* __restrict__ eh, float* __restrict__ energy) {
    int w = blockIdx.x * 4 + (threadIdx.x >> 6);
    int lane = threadIdx.x & 63;
    int s = w >> 9, b = w & 511;
    const __bf16* row = es + ((size_t)s * BATCH + b) * (2 * HSZ);
    float v = 0.f;
    for (int k = lane; k < 2 * HSZ; k += 64) v += (float)row[k] * eW2[k];
    for (int off = 32; off; off >>= 1) v += __shfl_down(v, off);
    if (lane == 0) energy[(size_t)s * BATCH + b] = fmaxf(v + eh[b], 0.f);
}

__global__ void softmax_kernel(const float* __restrict__ energy, float* __restrict__ attn) {
    int b = blockIdx.x * 4 + (threadIdx.x >> 6);
    int lane = threadIdx.x & 63;
    if (b >= BATCH) return;
    float v = energy[(size_t)lane * BATCH + b];
    float m = v;
    for (int off = 32; off; off >>= 1) m = fmaxf(m, __shfl_xor(m, off));
    float e = __expf(v - m);
    float sum = e;
    for (int off = 32; off; off >>= 1) sum += __shfl_xor(sum, off);
    attn[(size_t)lane * BATCH + b] = e / sum;
}

__global__ void context_kernel(const float* __restrict__ attn, const __bf16* __restrict__ es,
                               float* __restrict__ ctx) {
    int b = blockIdx.x;
    int j = threadIdx.x * 4;
    float a0 = 0.f, a1 = 0.f, a2 = 0.f, a3 = 0.f;
    for (int s = 0; s < SRCL; ++s) {
        float a = attn[(size_t)s * BATCH + b];
        const __bf16* r = es + ((size_t)s * BATCH + b) * (2 * HSZ) + j;
        a0 += a * (float)r[0]; a1 += a * (float)r[1];
        a2 += a * (float)r[2]; a3 += a * (float)r[3];
    }
    float4 o = make_float4(a0, a1, a2, a3);
    *(float4*)(ctx + (size_t)b * (2 * HSZ) + j) = o;
}

// ---------------- launch ----------------
extern "C" void kernel_launch(void* const* d_in, const int* in_sizes, int n_in,
                              void* d_out, int out_size, void* d_ws, size_t ws_size,
                              hipStream_t stream) {
    const int*   src      = (const int*)d_in[0];
    const int*   trg      = (const int*)d_in[1];
    const float* enc_emb  = (const float*)d_in[2];
    const float* Wih_f    = (const float*)d_in[3];
    const float* Whh_f    = (const float*)d_in[4];
    const float* bih_f    = (const float*)d_in[5];
    const float* bhh_f    = (const float*)d_in[6];
    const float* Wih_b    = (const float*)d_in[7];
    const float* Whh_b    = (const float*)d_in[8];
    const float* bih_b    = (const float*)d_in[9];
    const float* bhh_b    = (const float*)d_in[10];
    const float* fc_h_W   = (const float*)d_in[11];
    const float* fc_h_b   = (const float*)d_in[12];
    const float* fc_c_W   = (const float*)d_in[13];
    const float* fc_c_b   = (const float*)d_in[14];
    const float* dec_emb  = (const float*)d_in[15];
    const float* dec_Wih  = (const float*)d_in[16];
    const float* dec_Whh  = (const float*)d_in[17];
    const float* dec_bih  = (const float*)d_in[18];
    const float* dec_bhh  = (const float*)d_in[19];
    const float* energy_W = (const float*)d_in[20];
    const float* energy_b = (const float*)d_in[21];
    const float* fc_out_W = (const float*)d_in[22];
    const float* fc_out_b = (const float*)d_in[23];
    float* out = (float*)d_out;

    // workspace layout (float units, 16B aligned); total ~166 MB
    float* ws = (float*)d_ws;
    size_t o = 0;
    __bf16* Az   = (__bf16*)(ws + o); o += 4194304;   // enc x A-frags
    __bf16* Dz   = (__bf16*)(ws + o); o += 3080192;   // dec emb A-frags (1504*8*64*8)
    __bf16* es   = (__bf16*)(ws + o); o += 16777216;  // 64*512*1024 bf16
    float* zbase = ws + o;                            // h0,h1,cbuf contiguous
    __bf16* h0   = (__bf16*)(ws + o); o += 262144;    // frag-order h
    __bf16* h1   = (__bf16*)(ws + o); o += 262144;
    float*  cbuf = ws + o;            o += 524288;    // 2*512*512 f32
    __bf16* WzF  = (__bf16*)(ws + o); o += 786432;    // enc B-frags
    __bf16* WzB  = (__bf16*)(ws + o); o += 786432;
    __bf16* decWzp=(__bf16*)(ws + o); o += 262144;    // dec emb B-frags
    __bf16* WdC  = (__bf16*)(ws + o); o += 1572864;   // 2048*1536 row-major
    __bf16* WdZ  = (__bf16*)(ws + o); o += 1572864;   // frag order
    __bf16* fcWh = (__bf16*)(ws + o); o += 262144;
    __bf16* fcWhZ= (__bf16*)(ws + o); o += 262144;
    __bf16* fcWc = (__bf16*)(ws + o); o += 262144;
    __bf16* fcWcZ= (__bf16*)(ws + o); o += 262144;
    __bf16* foWb = (__bf16*)(ws + o); o += 32768;     // 128*512
    __bf16* foWz = (__bf16*)(ws + o); o += 32768;
    __bf16* hfb  = (__bf16*)(ws + o); o += 262144;
    __bf16* cfb  = (__bf16*)(ws + o); o += 262144;
    __bf16* ctxh = (__bf16*)(ws + o); o += 393216;
    float* hid_h = ws + o;            o += 262144;
    float* hid_c = ws + o;            o += 262144;
    float* ehv   = ws + o;            o += 512;
    float* energy= ws + o;            o += 32768;
    float* attn  = ws + o;            o += 32768;
    float* ctx   = ws + o;            o += 524288;
    float* D0    = ws + o;            o += 1048576;
    float* D0s   = ws + o;            o += 1048576;
    float* bias_f= ws + o;            o += 2048;
    float* bias_b= ws + o;            o += 2048;
    float* bias_d= ws + o;            o += 2048;
    __bf16* h_new= (__bf16*)(ws + o); o += 6160384;

    // ---- prep ----
    embed_swz<<<4096, 256, 0, stream>>>(src, enc_emb, Az);
    embdz<<<3008, 256, 0, stream>>>(trg, dec_emb, Dz);
    zero_kernel<<<4096, 256, 0, stream>>>(zbase, 1048576);     // h0,h1,cbuf
    bias_prep<<<8, 256, 0, stream>>>(bih_f, bhh_f, bih_b, bhh_b, dec_bih, dec_bhh,
                                     bias_f, bias_b, bias_d);
    wswz_bf16<<<768, 256, 0, stream>>>(Wih_f, Whh_f, WzF);
    wswz_bf16<<<768, 256, 0, stream>>>(Wih_b, Whh_b, WzB);
    decwz<<<256, 256, 0, stream>>>(dec_Wih, decWzp);
    wdcat_bf16<<<1536, 256, 0, stream>>>(dec_Wih, dec_Whh, WdC);
    fragswz<<<1536, 256, 0, stream>>>(WdC, WdZ, 48, 393216);
    conv_f2b<<<256, 256, 0, stream>>>(fc_h_W, fcWh, 65536);
    fragswz<<<256, 256, 0, stream>>>(fcWh, fcWhZ, 32, 65536);
    conv_f2b<<<256, 256, 0, stream>>>(fc_c_W, fcWc, 65536);
    fragswz<<<256, 256, 0, stream>>>(fcWc, fcWcZ, 32, 65536);
    fo_pad<<<32, 256, 0, stream>>>(fc_out_W, foWb);
    fragswz<<<32, 256, 0, stream>>>(foWb, foWz, 16, 8192);

    // ---- encoder scan: 64 per-step launches, 8 waves/CU, Whh LDS-resident per block ----
    for (int t = 0; t < SRCL; ++t) {
        const __bf16* hp = (t & 1) ? h1 : h0;
        __bf16*       hn = (t & 1) ? h0 : h1;
        enc_step6<<<dim3(32, 8, 2), 256, 0, stream>>>(
            Az, hp, hn, cbuf, es, WzF, WzB, bias_f, bias_b, t);
    }

    // ---- hidden projections ----
    cat_hfb<<<256, 256, 0, stream>>>(es, hfb);
    cat_cfb<<<256, 256, 0, stream>>>(cbuf, cfb);
    gmmz<<<dim3(8, 8), 256, 0, stream>>>(hfb, fcWhZ, 1024, 32, fc_h_b, hid_h, HSZ, HSZ);
    gmmz<<<dim3(8, 8), 256, 0, stream>>>(cfb, fcWcZ, 1024, 32, fc_c_b, hid_c, HSZ, HSZ);

    // ---- attention ----
    eh_kernel<<<128, 256, 0, stream>>>(hid_h, energy_W, energy_b, ehv);
    energy_kernel<<<8192, 256, 0, stream>>>(es, energy_W + HSZ, ehv, energy);
    softmax_kernel<<<128, 256, 0, stream>>>(energy, attn);
    context_kernel<<<512, 256, 0, stream>>>(attn, es, ctx);

    // ---- decoder batch-invariant: D0 = [ctx|hid_h] @ [Wih(:,:1024)|Whh]^T + bias ----
    cat_ctxh<<<384, 256, 0, stream>>>(ctx, hid_h, ctxh);
    gmmz<<<dim3(32, 8), 256, 0, stream>>>(ctxh, WdZ, 1536, 48, bias_d, D0, G4, G4);
    d0_swz<<<4096, 256, 0, stream>>>(D0, D0s);

    // ---- decoder fused gates + pointwise -> h_new (bf16) ----
    dec_v6<<<dim3(32, 94), 256, 0, stream>>>(Dz, decWzp, D0s, hid_c, h_new);

    // ---- outputs ----
    zero_kernel<<<134, 256, 0, stream>>>(out, BATCH * ODIM);
    gmmz<<<dim3(2, 376), 256, 0, stream>>>(h_new, foWz, HSZ, 16, fc_out_b,
                                           out + (size_t)BATCH * ODIM, ODIM, ODIM);
}